// Round 6
// baseline (58.499 us; speedup 1.0000x reference)
//
#include <hip/hip_runtime.h>
#include <hip/hip_bf16.h>

#define BB 2
#define DD 160
#define HH 192
#define WW 160

// Block = 32(w) x 8(h) threads, each thread does 4 d-slices.
// XCD-swizzled 1D grid (9600 blocks): each XCD owns a contiguous 10-slab
// z-range (~5 MB vol footprint ~ its 4 MB L2), (x,y) fastest within XCD.
// sched_barrier(0) after the 16 gather issues: R3/R4 showed the scheduler
// re-serializes them to hold VGPR_Count=32; the barrier forces all 16 loads
// outstanding (one latency exposure) with incremental vmcnt on the uses.

__device__ __forceinline__ float2 ld2(const float* __restrict__ vb, int off) {
    float2 v;
    __builtin_memcpy(&v, vb + off, 8);   // global_load_dwordx2, base+voffset
    return v;
}

struct Gp {
    int off;          // element offset of (d0,h0,wp)
    int d1o, h1o;     // element deltas (0 or stride)
    float tw, th, td;
};

__device__ __forceinline__ Gp prep(float ld, float lh, float lw) {
    ld = fminf(fmaxf(ld, 0.0f), (float)(DD - 1));
    lh = fminf(fmaxf(lh, 0.0f), (float)(HH - 1));
    lw = fminf(fmaxf(lw, 0.0f), (float)(WW - 1));

    float fd0 = floorf(ld), fh0 = floorf(lh), fw0 = floorf(lw);

    int d0 = (int)fd0, h0 = (int)fh0, w0 = (int)fw0;
    int d1 = min(d0 + 1, DD - 1);
    int h1 = min(h0 + 1, HH - 1);
    int wp = min(w0, WW - 2);   // pair-load: exact (tw==0 when w0==W-1)

    Gp g;
    g.td = ld - fd0;
    g.th = lh - fh0;
    g.tw = (lw - fw0) + (float)(w0 - wp);
    g.d1o = (d1 - d0) * (HH * WW);
    g.h1o = (h1 - h0) * WW;
    g.off = d0 * (HH * WW) + h0 * WW + wp;
    return g;
}

__device__ __forceinline__ float finish(const Gp& g, float2 a00, float2 a01,
                                        float2 a10, float2 a11) {
    float x00 = a00.x + g.tw * (a00.y - a00.x);
    float x01 = a01.x + g.tw * (a01.y - a01.x);
    float x10 = a10.x + g.tw * (a10.y - a10.x);
    float x11 = a11.x + g.tw * (a11.y - a11.x);
    float y0 = x00 + g.th * (x01 - x00);
    float y1 = x10 + g.th * (x11 - x10);
    return y0 + g.td * (y1 - y0);
}

__global__ void __launch_bounds__(256, 4)
st_trilinear_mlp2(const float* __restrict__ vol,
                  const float* __restrict__ shift,
                  float* __restrict__ out) {
    // XCD-aware decomposition of 9600 blocks = (5 x, 24 y, 80 z)
    int bid = blockIdx.x;
    int xcd = bid & 7;
    int rank = bid >> 3;           // 0..1199
    int zl = rank / 120;           // 0..9
    int xy = rank % 120;
    int by = xy / 5;               // 0..23
    int bx = xy - by * 5;          // 0..4
    int z = xcd * 10 + zl;         // 0..79
    int b = z / 40;
    int d0 = (z - b * 40) * 4;

    const int w = bx * 32 + threadIdx.x;
    const int h = by * 8 + threadIdx.y;

    const float* __restrict__ vb = vol + (long)b * (DD * HH * WW);
    const long sD = (long)HH * WW;
    const long idx = (((long)b * DD + d0) * HH + h) * WW + w;

    const float fh = (float)h, fw = (float)w;
    const float fd = (float)d0;

    // --- phase 1: all shift loads (independent, coalesced dwordx3) ---
    float3 s0, s1, s2, s3;
    __builtin_memcpy(&s0, shift + (idx + 0 * sD) * 3, 12);
    __builtin_memcpy(&s1, shift + (idx + 1 * sD) * 3, 12);
    __builtin_memcpy(&s2, shift + (idx + 2 * sD) * 3, 12);
    __builtin_memcpy(&s3, shift + (idx + 3 * sD) * 3, 12);

    // --- phase 2: all gather descriptors (VALU only, 32-bit offsets) ---
    Gp g0 = prep(fd + 0.0f + s0.x, fh + s0.y, fw + s0.z);
    Gp g1 = prep(fd + 1.0f + s1.x, fh + s1.y, fw + s1.z);
    Gp g2 = prep(fd + 2.0f + s2.x, fh + s2.y, fw + s2.z);
    Gp g3 = prep(fd + 3.0f + s3.x, fh + s3.y, fw + s3.z);

    // --- phase 3: issue all 16 pair-gathers, pinned before any use ---
    float2 a0_00 = ld2(vb, g0.off);
    float2 a0_01 = ld2(vb, g0.off + g0.h1o);
    float2 a0_10 = ld2(vb, g0.off + g0.d1o);
    float2 a0_11 = ld2(vb, g0.off + g0.d1o + g0.h1o);

    float2 a1_00 = ld2(vb, g1.off);
    float2 a1_01 = ld2(vb, g1.off + g1.h1o);
    float2 a1_10 = ld2(vb, g1.off + g1.d1o);
    float2 a1_11 = ld2(vb, g1.off + g1.d1o + g1.h1o);

    float2 a2_00 = ld2(vb, g2.off);
    float2 a2_01 = ld2(vb, g2.off + g2.h1o);
    float2 a2_10 = ld2(vb, g2.off + g2.d1o);
    float2 a2_11 = ld2(vb, g2.off + g2.d1o + g2.h1o);

    float2 a3_00 = ld2(vb, g3.off);
    float2 a3_01 = ld2(vb, g3.off + g3.h1o);
    float2 a3_10 = ld2(vb, g3.off + g3.d1o);
    float2 a3_11 = ld2(vb, g3.off + g3.d1o + g3.h1o);

    // nothing may cross: all 16 loads stay issued above, all math below
    __builtin_amdgcn_sched_barrier(0);

    // --- phase 4: finish + nontemporal stores (in load order, so the
    // waitcnt inserter emits incremental vmcnt and overlaps lerp w/ loads) ---
    __builtin_nontemporal_store(finish(g0, a0_00, a0_01, a0_10, a0_11), out + idx + 0 * sD);
    __builtin_nontemporal_store(finish(g1, a1_00, a1_01, a1_10, a1_11), out + idx + 1 * sD);
    __builtin_nontemporal_store(finish(g2, a2_00, a2_01, a2_10, a2_11), out + idx + 2 * sD);
    __builtin_nontemporal_store(finish(g3, a3_00, a3_01, a3_10, a3_11), out + idx + 3 * sD);
}

extern "C" void kernel_launch(void* const* d_in, const int* in_sizes, int n_in,
                              void* d_out, int out_size, void* d_ws, size_t ws_size,
                              hipStream_t stream) {
    const float* vol   = (const float*)d_in[0];
    const float* shift = (const float*)d_in[1];
    float* out = (float*)d_out;

    dim3 block(32, 8, 1);
    int grid = (WW / 32) * (HH / 8) * (DD / 4) * BB;   // 9600

    st_trilinear_mlp2<<<grid, block, 0, stream>>>(vol, shift, out);
}

// Round 7
// 44.830 us; speedup vs baseline: 1.3049x; 1.3049x over previous
//
#include <hip/hip_runtime.h>
#include <hip/hip_bf16.h>

#define BB 2
#define DD 160
#define HH 192
#define WW 160
#define SDp (HH * WW)          // 30720

// LDS tile: d in [d0-4, d0+8] (13), h in [h0-4, h0+11] (16), w in [w0-8, w0+39] (48)
#define TD 13
#define TH 16
#define TWf 48
#define ROWS (TD * TH)         // 208
#define NF4 (ROWS * TWf / 4)   // 2496 float4 slots
#define NITER 10               // ceil(2496/256)
#define TPAD (NITER * 1024)    // 10240 floats = 40960 B LDS (padded for tail)

__device__ __forceinline__ float2 ld2(const float* __restrict__ vb, int off) {
    float2 v;
    __builtin_memcpy(&v, vb + off, 8);   // global_load_dwordx2
    return v;
}

__device__ __forceinline__ void gload_lds16(const float* g, float* l) {
    __builtin_amdgcn_global_load_lds(
        (const __attribute__((address_space(1))) void*)g,
        (__attribute__((address_space(3))) void*)l, 16, 0, 0);
}

__global__ void __launch_bounds__(256, 4)
st_trilinear_lds(const float* __restrict__ vol,
                 const float* __restrict__ shift,
                 float* __restrict__ out) {
    __shared__ float tile[TPAD];

    // XCD-aware decomposition of 9600 blocks = (5 x, 24 y, 80 z)
    int bid = blockIdx.x;
    int xcd = bid & 7;
    int rank = bid >> 3;           // 0..1199
    int zl = rank / 120;           // 0..9
    int xy = rank % 120;
    int by = xy / 5;               // 0..23
    int bx = xy - by * 5;          // 0..4
    int z = xcd * 10 + zl;         // 0..79
    int b = z / 40;
    int d0 = (z - b * 40) * 4;

    const int tid = threadIdx.y * 32 + threadIdx.x;
    const int w = bx * 32 + threadIdx.x;
    const int h = by * 8 + threadIdx.y;

    const int dlo = d0 - 4;
    const int hlo = by * 8 - 4;
    const int wlo = bx * 32 - 8;   // 16B-aligned staging sources

    const float* __restrict__ vb = vol + (long)b * (DD * SDp);
    const long idx = (((long)b * DD + d0) * HH + h) * WW + w;

    // --- shift loads first: latency hides under the staging issues ---
    float3 s0, s1, s2, s3;
    __builtin_memcpy(&s0, shift + (idx + 0 * SDp) * 3, 12);
    __builtin_memcpy(&s1, shift + (idx + 1 * SDp) * 3, 12);
    __builtin_memcpy(&s2, shift + (idx + 2 * SDp) * 3, 12);
    __builtin_memcpy(&s3, shift + (idx + 3 * SDp) * 3, 12);

    // --- stage vol tile: 10 async global->LDS issues, 16B/lane, coalesced ---
    // slot 4e..4e+3 (e = i*256+tid) <-> tile[(row= e/12)][c = (e%12)*4 .. +3],
    // row = dd*16+hh. Out-of-volume slots get clamped (garbage) data but are
    // never read: sample coords are clamped to the volume, which lies in-tile.
    float* lbase = tile + (tid >> 6) * 256;   // wave-uniform base
#pragma unroll
    for (int i = 0; i < NITER; ++i) {
        int e = min(i * 256 + tid, NF4 - 1);   // tail: dup source, dest in pad
        int row = e / 12;
        int c4 = (e - row * 12) << 2;
        int dd = row >> 4, hh = row & 15;
        int dsrc = min(max(dlo + dd, 0), DD - 1);
        int hsrc = min(max(hlo + hh, 0), HH - 1);
        int wsrc = min(max(wlo + c4, 0), WW - 4);
        gload_lds16(vb + dsrc * SDp + hsrc * WW + wsrc, lbase + i * 1024);
    }
    __syncthreads();   // drains vmcnt (staging + shift)

    const float fd = (float)d0, fh = (float)h, fw = (float)w;

#pragma unroll
    for (int j = 0; j < 4; ++j) {
        float3 s = (j == 0) ? s0 : (j == 1) ? s1 : (j == 2) ? s2 : s3;

        float ldc = fminf(fmaxf(fd + (float)j + s.x, 0.0f), (float)(DD - 1));
        float lhc = fminf(fmaxf(fh + s.y, 0.0f), (float)(HH - 1));
        float lwc = fminf(fmaxf(fw + s.z, 0.0f), (float)(WW - 1));

        float fd0 = floorf(ldc), fh0 = floorf(lhc), fw0 = floorf(lwc);
        int d0c = (int)fd0, h0c = (int)fh0, w0c = (int)fw0;
        int d1c = min(d0c + 1, DD - 1);
        int h1c = min(h0c + 1, HH - 1);
        int wp  = min(w0c, WW - 2);          // pair-load (exact: tw==0 at edge)

        float td_ = ldc - fd0;
        float th_ = lhc - fh0;
        float tw_ = (lwc - fw0) + (float)(w0c - wp);

        float2 a00, a01, a10, a11;
        // exact integer in-tile test; fallback guarantees correctness for any shift
        bool ok = (d0c >= dlo) & (d1c <= dlo + TD - 1) &
                  (h0c >= hlo) & (h1c <= hlo + TH - 1) &
                  (wp >= wlo) & (wp + 1 <= wlo + TWf - 1);
        if (__builtin_expect(ok, 1)) {
            int lo  = ((d0c - dlo) * TH + (h0c - hlo)) * TWf + (wp - wlo);
            int d1l = (d1c - d0c) * (TH * TWf);
            int h1l = (h1c - h0c) * TWf;
            a00 = make_float2(tile[lo], tile[lo + 1]);
            a01 = make_float2(tile[lo + h1l], tile[lo + h1l + 1]);
            a10 = make_float2(tile[lo + d1l], tile[lo + d1l + 1]);
            a11 = make_float2(tile[lo + d1l + h1l], tile[lo + d1l + h1l + 1]);
        } else {
            int go = d0c * SDp + h0c * WW + wp;
            int gd = (d1c - d0c) * SDp;
            int gh = (h1c - h0c) * WW;
            a00 = ld2(vb, go);
            a01 = ld2(vb, go + gh);
            a10 = ld2(vb, go + gd);
            a11 = ld2(vb, go + gd + gh);
        }

        float x00 = a00.x + tw_ * (a00.y - a00.x);
        float x01 = a01.x + tw_ * (a01.y - a01.x);
        float x10 = a10.x + tw_ * (a10.y - a10.x);
        float x11 = a11.x + tw_ * (a11.y - a11.x);
        float y0 = x00 + th_ * (x01 - x00);
        float y1 = x10 + th_ * (x11 - x10);
        float r = y0 + td_ * (y1 - y0);

        __builtin_nontemporal_store(r, out + idx + (long)j * SDp);
    }
}

extern "C" void kernel_launch(void* const* d_in, const int* in_sizes, int n_in,
                              void* d_out, int out_size, void* d_ws, size_t ws_size,
                              hipStream_t stream) {
    const float* vol   = (const float*)d_in[0];
    const float* shift = (const float*)d_in[1];
    float* out = (float*)d_out;

    dim3 block(32, 8, 1);
    int grid = (WW / 32) * (HH / 8) * (DD / 4) * BB;   // 9600

    st_trilinear_lds<<<grid, block, 0, stream>>>(vol, shift, out);
}